// Round 6
// baseline (174.463 us; speedup 1.0000x reference)
//
#include <hip/hip_runtime.h>
#include <hip/hip_bf16.h>
#include <math.h>

#define BB 2
#define NN 65000
#define MM 64
#define DIM 192
#define NH 4
#define HD 48
#define GS 128
#define NG 508            // ceil(65000/128)
#define SORT_TPB 256
#define NBLK 254          // ceil(65000/256)

#define XROWS 65024       // NN padded to 64-row tiles (per b)
#define XTILES_B 1016     // XROWS/64

typedef __attribute__((ext_vector_type(8))) short bf16x8;
typedef __attribute__((ext_vector_type(8))) _Float16 f16x8;
typedef __attribute__((ext_vector_type(2))) __fp16 fp16x2;
typedef __attribute__((ext_vector_type(4))) float f32x4;
typedef __attribute__((ext_vector_type(16))) float f32x16;
typedef __attribute__((ext_vector_type(8))) unsigned short u16x8;

__device__ __forceinline__ unsigned short f2bf(float f) {
  __hip_bfloat16 h = __float2bfloat16(f);
  return *(unsigned short*)&h;
}
// pack two f32 -> two f16 in one uint (v_cvt_pkrtz_f16_f32)
__device__ __forceinline__ unsigned int pkh(float lo, float hi) {
  fp16x2 t = __builtin_amdgcn_cvt_pkrtz(lo, hi);
  return *(unsigned int*)&t;
}
__device__ __forceinline__ f16x8 cvt8h(float4 a, float4 b) {
  f16x8 r;
  r[0] = (_Float16)a.x; r[1] = (_Float16)a.y; r[2] = (_Float16)a.z; r[3] = (_Float16)a.w;
  r[4] = (_Float16)b.x; r[5] = (_Float16)b.y; r[6] = (_Float16)b.z; r[7] = (_Float16)b.w;
  return r;
}
// async global->LDS, 16B per lane; dest = lds_base + lane*16 (linear)
__device__ __forceinline__ void gload_lds16(const float* src, float* lds_dst) {
  __builtin_amdgcn_global_load_lds(
      (const __attribute__((address_space(1))) unsigned int*)src,
      (__attribute__((address_space(3))) unsigned int*)lds_dst, 16, 0, 0);
}

// ---------------- K1: fused per-token argmax + per-block histogram --------
__global__ void k_argmax_hist(const float* __restrict__ sim, int* __restrict__ tk,
                              int* __restrict__ hist) {
  __shared__ int cnt[MM];
  const int b = blockIdx.y, blk = blockIdx.x;
  if (threadIdx.x < MM) cnt[threadIdx.x] = 0;
  __syncthreads();
  int t = blk * SORT_TPB + threadIdx.x;
  if (t < NN) {
    const float4* row = (const float4*)(sim + ((size_t)b * NN + t) * MM);
    float best = -INFINITY;
    int bi = 0;
#pragma unroll
    for (int j = 0; j < MM / 4; ++j) {
      float4 v = row[j];
      if (v.x > best) { best = v.x; bi = 4 * j + 0; }
      if (v.y > best) { best = v.y; bi = 4 * j + 1; }
      if (v.z > best) { best = v.z; bi = 4 * j + 2; }
      if (v.w > best) { best = v.w; bi = 4 * j + 3; }
    }
    tk[b * NN + t] = bi;
    atomicAdd(&cnt[bi], 1);
  }
  __syncthreads();
  if (threadIdx.x < MM)
    hist[(b * NBLK + blk) * MM + threadIdx.x] = cnt[threadIdx.x];
}

// ---------------- K3: scan (1024 threads: 16 segments x 64 bins) ----------
#define SEGS 16
#define SEGB 16   // blocks per segment (16*16=256 >= NBLK)
__global__ void k_scan(const int* __restrict__ hist, int* __restrict__ boff) {
  const int b = blockIdx.x;
  const int tid = threadIdx.x;
  const int seg = tid >> 6, bin = tid & 63;
  __shared__ int part[SEGS][MM];
  __shared__ int basev[MM];
  const int lo = seg * SEGB;
  const int hi = min(NBLK, lo + SEGB);
  int s = 0;
  for (int blk = lo; blk < hi; ++blk) s += hist[(b * NBLK + blk) * MM + bin];
  part[seg][bin] = s;
  __syncthreads();
  if (tid < 64) {
    int tot = 0;
#pragma unroll
    for (int s2 = 0; s2 < SEGS; ++s2) tot += part[s2][bin];
    int incl = tot;
#pragma unroll
    for (int d = 1; d < 64; d <<= 1) {
      int o = __shfl_up(incl, d);
      if (bin >= d) incl += o;
    }
    basev[bin] = incl - tot;   // exclusive prefix over bins
  }
  __syncthreads();
  int run = basev[bin];
  for (int s2 = 0; s2 < seg; ++s2) run += part[s2][bin];
  for (int blk = lo; blk < hi; ++blk) {
    int h = hist[(b * NBLK + blk) * MM + bin];
    boff[(b * NBLK + blk) * MM + bin] = run;
    run += h;
  }
}

// ---------------- K4: stable scatter → sort_idx (ballot rank) -------------
__global__ void k_scatter(const int* __restrict__ tk, const int* __restrict__ boff,
                          int* __restrict__ sidx) {
  __shared__ int whist[4][MM];
  const int b = blockIdx.y, blk = blockIdx.x;
  const int tid = threadIdx.x;
  const int w = tid >> 6, lane = tid & 63;
  ((int*)whist)[tid] = 0;   // 256 == 4*MM
  __syncthreads();
  int t = blk * SORT_TPB + tid;
  int bin = (t < NN) ? tk[b * NN + t] : -1;
  unsigned long long m = ~0ull;
#pragma unroll
  for (int bit = 0; bit < 6; ++bit) {
    unsigned long long bl = __ballot((bin >> bit) & 1);
    m &= ((bin >> bit) & 1) ? bl : ~bl;
  }
  int rank_w = __popcll(m & ((1ull << lane) - 1ull));
  if (bin >= 0 && rank_w == 0) whist[w][bin] = __popcll(m);
  __syncthreads();
  if (bin >= 0) {
    int rank = rank_w;
#pragma unroll
    for (int w2 = 0; w2 < 3; ++w2)
      if (w2 < w) rank += whist[w2][bin];
    int pos = boff[(b * NBLK + blk) * MM + bin] + rank;
    sidx[b * NN + pos] = t;
  }
}

// ---------------- K5: MFMA group attention, ALL-HEAD 1024-thread blocks ----
// Block = 1024 threads = 4 head-subgroups x 4 waves, one (b, g). All 16 waves
// issue their gathers CONCURRENTLY at block start, so each token row's 12
// disjoint 192B slices (the full 2304B row) are requested from one CU within
// the same time window -> near-full DRAM page utilization (vs ~50% for
// isolated 192B random reads). LDS = 112.5 KB -> 1 block/CU = 16 waves/CU
// (up from 12). Per-head compute/cvt/MFMA order bit-identical to r5.
// __launch_bounds__(1024) caps VGPR at 128 (PV-phase live set ~110-120).
__global__ __launch_bounds__(1024) void k_attn_mfma(const float* __restrict__ qkv,
                                                    const int* __restrict__ sidx,
                                                    const float* __restrict__ logit_scale,
                                                    __hip_bfloat16* __restrict__ attn_out) {
  const int g = blockIdx.x;                 // 0..507
  const int b = blockIdx.z;

  __shared__ int stok[GS];
  __shared__ __align__(16) _Float16 akv[NH][4 * 3 * 64 * 8];    // K A-frags (4x12 KB)
  __shared__ __align__(16) _Float16 vfrag[NH][2 * 8 * 64 * 8];  // V B-frags (4x16 KB)

  const int tid = threadIdx.x;
  const int hd = tid >> 8;        // head-subgroup (wave-uniform)
  const int t256 = tid & 255;     // index within subgroup
  const int w = t256 >> 6, l = tid & 63;
  const int hl = l >> 5, l31 = l & 31;

  if (tid < GS) {
    int s = g * GS + tid;
    int sp = (s < NN) ? s : (2 * NN - 1 - s);   // reflect padding
    stok[tid] = sidx[b * NN + sp];
  }
  __syncthreads();

  // --- K A-frags: stage directly in fragment order (lane-linear 16B) ---
#pragma unroll
  for (int i = 0; i < 3; ++i) {
    int c = t256 + 256 * i;                  // (t*3+s)*64 + lane
    int ts = c >> 6, cl = c & 63;
    int kvr = (ts / 3) * 32 + (cl & 31);
    int dbase = (ts % 3) * 16 + (cl >> 5) * 8;
    const float* src = qkv + (size_t)(b * NN + stok[kvr]) * (3 * DIM) + DIM + hd * HD + dbase;
    ((f16x8*)akv[hd])[c] = cvt8h(((const float4*)src)[0], ((const float4*)src)[1]);
  }

  // --- V B-frags: direct global gather in frag order ---
#pragma unroll
  for (int i = 0; i < 4; ++i) {
    int c = t256 + 256 * i;                  // (nt*8+ks)*64 + lane
    int ntks = c >> 6, cl = c & 63;
    int nt = ntks >> 3, ks = ntks & 7;
    int d = nt * 32 + (cl & 31);
    int kvb = ks * 16 + (cl >> 5) * 8;
    _Float16 tmp[8];
    if (d < HD) {
#pragma unroll
      for (int e = 0; e < 8; ++e)
        tmp[e] = (_Float16)qkv[(size_t)(b * NN + stok[kvb + e]) * (3 * DIM) + 2 * DIM + hd * HD + d];
    } else {
#pragma unroll
      for (int e = 0; e < 8; ++e) tmp[e] = (_Float16)0.f;
    }
    ((f16x8*)vfrag[hd])[c] = *(f16x8*)tmp;
  }

  // --- Q B-frags: per-lane direct global load (no LDS) ---
  f16x8 qf[3];
  {
    const float* qsrc = qkv + (size_t)(b * NN + stok[w * 32 + l31]) * (3 * DIM) + hd * HD;
#pragma unroll
    for (int s = 0; s < 3; ++s) {
      const float4* p = (const float4*)(qsrc + s * 16 + hl * 8);
      qf[s] = cvt8h(p[0], p[1]);
    }
  }
  __syncthreads();   // all heads' akv + vfrag ready

  // --- QK^T: 4 kv-tiles x 3 d-steps ---
  f32x16 accS[4];
#pragma unroll
  for (int t = 0; t < 4; ++t)
#pragma unroll
    for (int r = 0; r < 16; ++r) accS[t][r] = 0.f;

#pragma unroll
  for (int t = 0; t < 4; ++t)
#pragma unroll
    for (int s = 0; s < 3; ++s) {
      f16x8 af = ((const f16x8*)akv[hd])[(t * 3 + s) * 64 + l];
      accS[t] = __builtin_amdgcn_mfma_f32_32x32x16_f16(af, qf[s], accS[t], 0, 0, 0);
    }

  // --- softmax (each lane: full row for q=32w+l31, split with lane^32) ---
  const float scale = expf(fminf(logit_scale[0], 4.6051701860f));
  float mx = -INFINITY;
#pragma unroll
  for (int t = 0; t < 4; ++t)
#pragma unroll
    for (int r = 0; r < 16; ++r) { accS[t][r] *= scale; mx = fmaxf(mx, accS[t][r]); }
  mx = fmaxf(mx, __shfl_xor(mx, 32));
  float sum = 0.f;
#pragma unroll
  for (int t = 0; t < 4; ++t)
#pragma unroll
    for (int r = 0; r < 16; ++r) { float p = __expf(accS[t][r] - mx); accS[t][r] = p; sum += p; }
  sum += __shfl_xor(sum, 32);
  const float inv = 1.f / sum;
#pragma unroll
  for (int t = 0; t < 4; ++t)
#pragma unroll
    for (int r = 0; r < 16; ++r) accS[t][r] *= inv;

  // --- PV: build P A-frags in-register, 2 d-tiles x 8 k-steps ---
  f32x16 accO[2];
#pragma unroll
  for (int nt = 0; nt < 2; ++nt)
#pragma unroll
    for (int r = 0; r < 16; ++r) accO[nt][r] = 0.f;

#pragma unroll
  for (int t = 0; t < 4; ++t) {
    union { unsigned int u[4]; f16x8 v; } fa, fb;
    {
      unsigned int a0 = pkh(accS[t][0], accS[t][1]);
      unsigned int a1 = pkh(accS[t][2], accS[t][3]);
      unsigned int b0 = pkh(accS[t][4], accS[t][5]);
      unsigned int b1 = pkh(accS[t][6], accS[t][7]);
      unsigned int sa0 = __shfl_xor(a0, 32), sa1 = __shfl_xor(a1, 32);
      unsigned int sb0 = __shfl_xor(b0, 32), sb1 = __shfl_xor(b1, 32);
      fa.u[0] = hl ? sb0 : a0; fa.u[1] = hl ? sb1 : a1;
      fa.u[2] = hl ? b0 : sa0; fa.u[3] = hl ? b1 : sa1;
    }
    {
      unsigned int a0 = pkh(accS[t][8], accS[t][9]);
      unsigned int a1 = pkh(accS[t][10], accS[t][11]);
      unsigned int b0 = pkh(accS[t][12], accS[t][13]);
      unsigned int b1 = pkh(accS[t][14], accS[t][15]);
      unsigned int sa0 = __shfl_xor(a0, 32), sa1 = __shfl_xor(a1, 32);
      unsigned int sb0 = __shfl_xor(b0, 32), sb1 = __shfl_xor(b1, 32);
      fb.u[0] = hl ? sb0 : a0; fb.u[1] = hl ? sb1 : a1;
      fb.u[2] = hl ? b0 : sa0; fb.u[3] = hl ? b1 : sa1;
    }
    accO[0] = __builtin_amdgcn_mfma_f32_32x32x16_f16(fa.v, ((const f16x8*)vfrag[hd])[(0 * 8 + 2 * t) * 64 + l], accO[0], 0, 0, 0);
    accO[1] = __builtin_amdgcn_mfma_f32_32x32x16_f16(fa.v, ((const f16x8*)vfrag[hd])[(1 * 8 + 2 * t) * 64 + l], accO[1], 0, 0, 0);
    accO[0] = __builtin_amdgcn_mfma_f32_32x32x16_f16(fb.v, ((const f16x8*)vfrag[hd])[(0 * 8 + 2 * t + 1) * 64 + l], accO[0], 0, 0, 0);
    accO[1] = __builtin_amdgcn_mfma_f32_32x32x16_f16(fb.v, ((const f16x8*)vfrag[hd])[(1 * 8 + 2 * t + 1) * 64 + l], accO[1], 0, 0, 0);
  }

  // --- store to SORTED position (linear, coalesced), bf16 ---
#pragma unroll
  for (int r = 0; r < 16; ++r) {
    int rowl = w * 32 + (r & 3) + 8 * (r >> 2) + 4 * hl;
    int sg = g * GS + rowl;
    if (sg < NN) {
      size_t base = ((size_t)b * XROWS + sg) * DIM + hd * HD;
      attn_out[base + l31] = __float2bfloat16(accO[0][r]);
      if (l31 < 16) attn_out[base + 32 + l31] = __float2bfloat16(accO[1][r]);
    }
  }
}

// ---------------- K6a: pack W into MFMA B-fragment order ------------------
__global__ void k_wpack(const float* __restrict__ W, unsigned short* __restrict__ wpack) {
  int idx = blockIdx.x * blockDim.x + threadIdx.x;
  if (idx >= 12 * 6 * 64) return;
  int lane = idx & 63;
  int kkjt = idx >> 6;
  int kk = kkjt % 6;
  int jt = kkjt / 6;
  int j = jt * 16 + (lane & 15);
  int k0 = kk * 32 + (lane >> 4) * 8;
  const float* src = W + (size_t)j * DIM + k0;
  unsigned short tmp[8];
#pragma unroll
  for (int e = 0; e < 8; ++e) tmp[e] = f2bf(src[e]);
  ((u16x8*)wpack)[idx] = *(const u16x8*)tmp;
}

// ---------------- K6b: projection (reads sorted x, scatters out) ----------
__global__ __launch_bounds__(256) void k_proj_mfma(const unsigned short* __restrict__ xb,
                                                   const int* __restrict__ sidx,
                                                   const unsigned short* __restrict__ wpack,
                                                   const float* __restrict__ bias,
                                                   float* __restrict__ out) {
  __shared__ unsigned short wl[12 * 6 * 64 * 8];   // 72 KB
  const int tid = threadIdx.x;

  // async stage: chunk c dest = base + c*16 (lane-linear per wave)
#pragma unroll
  for (int j = 0; j < 18; ++j) {
    int c = j * 256 + tid;
    gload_lds16((const float*)((const u16x8*)wpack + c), (float*)((u16x8*)wl + c));
  }

  const int wid = tid >> 6, lane = tid & 63;
  const int l15 = lane & 15, lk = lane >> 4;

  float bv[12];
#pragma unroll
  for (int jt = 0; jt < 12; ++jt) bv[jt] = bias[jt * 16 + l15];

  __syncthreads();   // drains gload_lds vmcnt

  for (int tile = blockIdx.x; tile < BB * XTILES_B; tile += gridDim.x) {
    const int b = tile / XTILES_B;
    const int r0 = (tile % XTILES_B) * 64 + wid * 16;   // sorted-row base
    f32x4 acc[12];
#pragma unroll
    for (int jt = 0; jt < 12; ++jt) { f32x4 t = {bv[jt], bv[jt], bv[jt], bv[jt]}; acc[jt] = t; }

    const unsigned short* xrow = xb + ((size_t)b * XROWS + r0 + l15) * DIM;
#pragma unroll
    for (int kk = 0; kk < 6; ++kk) {
      bf16x8 a = *(const bf16x8*)(xrow + kk * 32 + lk * 8);
#pragma unroll
      for (int jt = 0; jt < 12; ++jt) {
        bf16x8 bfr = *(const bf16x8*)(wl + ((jt * 6 + kk) * 64 + lane) * 8);
        acc[jt] = __builtin_amdgcn_mfma_f32_16x16x32_bf16(a, bfr, acc[jt], 0, 0, 0);
      }
    }

    const int rowb = r0 + lk * 4;
    int orow[4];
#pragma unroll
    for (int r = 0; r < 4; ++r)
      orow[r] = (rowb + r < NN) ? sidx[b * NN + rowb + r] : -1;

#pragma unroll
    for (int jt = 0; jt < 12; ++jt) {
#pragma unroll
      for (int r = 0; r < 4; ++r) {
        if (orow[r] >= 0)
          out[((size_t)b * NN + orow[r]) * DIM + jt * 16 + l15] = acc[jt][r];
      }
    }
  }
}

// ---------------- launch --------------------------------------------------
extern "C" void kernel_launch(void* const* d_in, const int* in_sizes, int n_in,
                              void* d_out, int out_size, void* d_ws, size_t ws_size,
                              hipStream_t stream) {
  const float* qkv = (const float*)d_in[0];
  const float* sim = (const float*)d_in[1];
  const float* proj_w = (const float*)d_in[2];
  const float* proj_b = (const float*)d_in[3];
  const float* logit_scale = (const float*)d_in[4];

  unsigned short* x_bf16 = (unsigned short*)d_ws;                 // BB*XROWS*DIM bf16
  unsigned short* wpack = x_bf16 + (size_t)BB * XROWS * DIM;      // 12*6*64*8
  int* tk = (int*)(wpack + 12 * 6 * 64 * 8);                      // BB*NN
  int* hist = tk + (size_t)BB * NN;                               // BB*NBLK*MM
  int* boff = hist + (size_t)BB * NBLK * MM;                      // BB*NBLK*MM
  int* sidx = boff + (size_t)BB * NBLK * MM;                      // BB*NN

  k_argmax_hist<<<dim3(NBLK, BB), SORT_TPB, 0, stream>>>(sim, tk, hist);
  k_scan<<<BB, 1024, 0, stream>>>(hist, boff);
  k_scatter<<<dim3(NBLK, BB), SORT_TPB, 0, stream>>>(tk, boff, sidx);
  k_wpack<<<(12 * 6 * 64 + 255) / 256, 256, 0, stream>>>(proj_w, wpack);
  k_attn_mfma<<<dim3(NG, 1, BB), 1024, 0, stream>>>(qkv, sidx, logit_scale,
                                                    (__hip_bfloat16*)x_bf16);
  k_proj_mfma<<<dim3(1016), 256, 0, stream>>>(x_bf16, sidx, wpack, proj_b, (float*)d_out);
}

// Round 7
// 158.641 us; speedup vs baseline: 1.0997x; 1.0997x over previous
//
#include <hip/hip_runtime.h>
#include <hip/hip_bf16.h>
#include <math.h>

#define BB 2
#define NN 65000
#define MM 64
#define DIM 192
#define NH 4
#define HD 48
#define GS 128
#define NG 508            // ceil(65000/128)
#define SORT_TPB 256
#define NBLK 254          // ceil(65000/256)

#define XROWS 65024       // NN padded to 64-row tiles (per b)
#define XTILES_B 1016     // XROWS/64

#define KVS 100           // LDS row stride (fp16) for K/V pair rows (96 used)

typedef __attribute__((ext_vector_type(8))) short bf16x8;
typedef __attribute__((ext_vector_type(8))) _Float16 f16x8;
typedef __attribute__((ext_vector_type(4))) _Float16 f16x4;
typedef __attribute__((ext_vector_type(2))) __fp16 fp16x2;
typedef __attribute__((ext_vector_type(4))) float f32x4;
typedef __attribute__((ext_vector_type(16))) float f32x16;
typedef __attribute__((ext_vector_type(8))) unsigned short u16x8;

__device__ __forceinline__ unsigned short f2bf(float f) {
  __hip_bfloat16 h = __float2bfloat16(f);
  return *(unsigned short*)&h;
}
// pack two f32 -> two f16 in one uint (v_cvt_pkrtz_f16_f32)
__device__ __forceinline__ unsigned int pkh(float lo, float hi) {
  fp16x2 t = __builtin_amdgcn_cvt_pkrtz(lo, hi);
  return *(unsigned int*)&t;
}
__device__ __forceinline__ f16x8 cvt8h(float4 a, float4 b) {
  f16x8 r;
  r[0] = (_Float16)a.x; r[1] = (_Float16)a.y; r[2] = (_Float16)a.z; r[3] = (_Float16)a.w;
  r[4] = (_Float16)b.x; r[5] = (_Float16)b.y; r[6] = (_Float16)b.z; r[7] = (_Float16)b.w;
  return r;
}
// async global->LDS, 16B per lane; dest = lds_base + lane*16 (linear)
__device__ __forceinline__ void gload_lds16(const float* src, float* lds_dst) {
  __builtin_amdgcn_global_load_lds(
      (const __attribute__((address_space(1))) unsigned int*)src,
      (__attribute__((address_space(3))) unsigned int*)lds_dst, 16, 0, 0);
}

// ---------------- K1: fused per-token argmax + per-block histogram --------
__global__ void k_argmax_hist(const float* __restrict__ sim, int* __restrict__ tk,
                              int* __restrict__ hist) {
  __shared__ int cnt[MM];
  const int b = blockIdx.y, blk = blockIdx.x;
  if (threadIdx.x < MM) cnt[threadIdx.x] = 0;
  __syncthreads();
  int t = blk * SORT_TPB + threadIdx.x;
  if (t < NN) {
    const float4* row = (const float4*)(sim + ((size_t)b * NN + t) * MM);
    float best = -INFINITY;
    int bi = 0;
#pragma unroll
    for (int j = 0; j < MM / 4; ++j) {
      float4 v = row[j];
      if (v.x > best) { best = v.x; bi = 4 * j + 0; }
      if (v.y > best) { best = v.y; bi = 4 * j + 1; }
      if (v.z > best) { best = v.z; bi = 4 * j + 2; }
      if (v.w > best) { best = v.w; bi = 4 * j + 3; }
    }
    tk[b * NN + t] = bi;
    atomicAdd(&cnt[bi], 1);
  }
  __syncthreads();
  if (threadIdx.x < MM)
    hist[(b * NBLK + blk) * MM + threadIdx.x] = cnt[threadIdx.x];
}

// ---------------- K3: scan (1024 threads: 16 segments x 64 bins) ----------
#define SEGS 16
#define SEGB 16   // blocks per segment (16*16=256 >= NBLK)
__global__ void k_scan(const int* __restrict__ hist, int* __restrict__ boff) {
  const int b = blockIdx.x;
  const int tid = threadIdx.x;
  const int seg = tid >> 6, bin = tid & 63;
  __shared__ int part[SEGS][MM];
  __shared__ int basev[MM];
  const int lo = seg * SEGB;
  const int hi = min(NBLK, lo + SEGB);
  int s = 0;
  for (int blk = lo; blk < hi; ++blk) s += hist[(b * NBLK + blk) * MM + bin];
  part[seg][bin] = s;
  __syncthreads();
  if (tid < 64) {
    int tot = 0;
#pragma unroll
    for (int s2 = 0; s2 < SEGS; ++s2) tot += part[s2][bin];
    int incl = tot;
#pragma unroll
    for (int d = 1; d < 64; d <<= 1) {
      int o = __shfl_up(incl, d);
      if (bin >= d) incl += o;
    }
    basev[bin] = incl - tot;   // exclusive prefix over bins
  }
  __syncthreads();
  int run = basev[bin];
  for (int s2 = 0; s2 < seg; ++s2) run += part[s2][bin];
  for (int blk = lo; blk < hi; ++blk) {
    int h = hist[(b * NBLK + blk) * MM + bin];
    boff[(b * NBLK + blk) * MM + bin] = run;
    run += h;
  }
}

// ---------------- K4: stable scatter → sort_idx (ballot rank) -------------
__global__ void k_scatter(const int* __restrict__ tk, const int* __restrict__ boff,
                          int* __restrict__ sidx) {
  __shared__ int whist[4][MM];
  const int b = blockIdx.y, blk = blockIdx.x;
  const int tid = threadIdx.x;
  const int w = tid >> 6, lane = tid & 63;
  ((int*)whist)[tid] = 0;   // 256 == 4*MM
  __syncthreads();
  int t = blk * SORT_TPB + tid;
  int bin = (t < NN) ? tk[b * NN + t] : -1;
  unsigned long long m = ~0ull;
#pragma unroll
  for (int bit = 0; bit < 6; ++bit) {
    unsigned long long bl = __ballot((bin >> bit) & 1);
    m &= ((bin >> bit) & 1) ? bl : ~bl;
  }
  int rank_w = __popcll(m & ((1ull << lane) - 1ull));
  if (bin >= 0 && rank_w == 0) whist[w][bin] = __popcll(m);
  __syncthreads();
  if (bin >= 0) {
    int rank = rank_w;
#pragma unroll
    for (int w2 = 0; w2 < 3; ++w2)
      if (w2 < w) rank += whist[w2][bin];
    int pos = boff[(b * NBLK + blk) * MM + bin] + rank;
    sidx[b * NN + pos] = t;
  }
}

// ---------------- K5: MFMA group attention, BURST-GATHER head-pair --------
// Block = 256 threads = 4 waves, one (b, g, head-pair p). The K-pair and
// V-pair slices of each token row (384B contiguous each) are staged into
// row-major LDS with ROW-CONTIGUOUS wave bursts: each wave instruction reads
// 64 consecutive float4 (1024B spanning ~2.7 rows); K and V loads for the
// same row issue back-to-back (same DRAM page). Q: 6 back-to-back float4 =
// 384B contiguous per lane. This raises DRAM page utilization vs the old
// frag-order gather (16-128B random granularity).
// MFMA operands read directly from padded LDS (stride 100 fp16):
//   K-frag: 2x ds_read_b64, rows at 2-way bank alias (free);
//   V-frag: 8x u16, lanes pair on words -> conflict-free.
// LDS = 0.5 + 2*25 = 50.5 KB -> 3 blocks/CU (12 waves, same as r5).
// Conversions are single RNE (_Float16) casts, MFMA order identical per
// head -> bitwise-identical output to r5.
__global__ __launch_bounds__(256, 3) void k_attn_mfma(const float* __restrict__ qkv,
                                                      const int* __restrict__ sidx,
                                                      const float* __restrict__ logit_scale,
                                                      __hip_bfloat16* __restrict__ attn_out) {
  const int x = blockIdx.x;                 // 1024 slots
  const int g = ((x >> 4) << 3) + (x & 7);  // pair-blocks of a group: 8 apart -> same XCD
  const int p = (x >> 3) & 1;               // head pair
  const int b = blockIdx.z;
  if (g >= NG) return;

  __shared__ int stok[GS];
  __shared__ __align__(16) _Float16 kls[GS * KVS];   // K pair rows, 25 KB
  __shared__ __align__(16) _Float16 vls[GS * KVS];   // V pair rows, 25 KB

  const int tid = threadIdx.x;
  const int w = tid >> 6, l = tid & 63;
  const int hl = l >> 5, l31 = l & 31;

  if (tid < GS) {
    int s = g * GS + tid;
    int sp = (s < NN) ? s : (2 * NN - 1 - s);   // reflect padding
    stok[tid] = sidx[b * NN + sp];
  }
  __syncthreads();

  // --- burst stage K+V pair slices, row-major fp16 LDS ---
  // chunk c: row = c/24, piece = c%24 (24 float4 = 384B per row slice).
  // Wave lanes have consecutive c -> contiguous 384B runs per row; K and V
  // of the same row back-to-back -> same page.
#pragma unroll
  for (int i = 0; i < 12; ++i) {
    int c = tid + 256 * i;
    int row = c / 24, piece = c % 24;
    const float* base = qkv + (size_t)(b * NN + stok[row]) * (3 * DIM) + 96 * p + piece * 4;
    float4 kv = *(const float4*)(base + DIM);        // K slice
    float4 vv = *(const float4*)(base + 2 * DIM);    // V slice
    f16x4 hk, hv;
    hk[0] = (_Float16)kv.x; hk[1] = (_Float16)kv.y; hk[2] = (_Float16)kv.z; hk[3] = (_Float16)kv.w;
    hv[0] = (_Float16)vv.x; hv[1] = (_Float16)vv.y; hv[2] = (_Float16)vv.z; hv[3] = (_Float16)vv.w;
    *(f16x4*)(kls + row * KVS + piece * 4) = hk;
    *(f16x4*)(vls + row * KVS + piece * 4) = hv;
  }

  // --- Q both heads: per-lane 384B contiguous (6 back-to-back float4) ---
  f16x8 qf[2][3];
  {
    const float* qsrc = qkv + (size_t)(b * NN + stok[w * 32 + l31]) * (3 * DIM) + 96 * p;
#pragma unroll
    for (int hh = 0; hh < 2; ++hh)
#pragma unroll
      for (int s = 0; s < 3; ++s) {
        const float4* pp = (const float4*)(qsrc + hh * 48 + s * 16 + hl * 8);
        qf[hh][s] = cvt8h(pp[0], pp[1]);
      }
  }
  __syncthreads();   // kls + vls ready

  const float scale = expf(fminf(logit_scale[0], 4.6051701860f));

  for (int hh = 0; hh < 2; ++hh) {
    const int hd = 2 * p + hh;

    // --- QK^T: 4 kv-tiles x 3 d-steps, K frags direct from LDS ---
    f32x16 accS[4];
#pragma unroll
    for (int t = 0; t < 4; ++t)
#pragma unroll
      for (int r = 0; r < 16; ++r) accS[t][r] = 0.f;

#pragma unroll
    for (int t = 0; t < 4; ++t)
#pragma unroll
      for (int s = 0; s < 3; ++s) {
        int kvr = t * 32 + l31;
        const f16x4* ka = (const f16x4*)(kls + kvr * KVS + hh * 48 + s * 16 + hl * 8);
        f16x4 a0 = ka[0], a1 = ka[1];
        f16x8 af;
        af[0] = a0[0]; af[1] = a0[1]; af[2] = a0[2]; af[3] = a0[3];
        af[4] = a1[0]; af[5] = a1[1]; af[6] = a1[2]; af[7] = a1[3];
        accS[t] = __builtin_amdgcn_mfma_f32_32x32x16_f16(af, qf[hh][s], accS[t], 0, 0, 0);
      }

    // --- softmax (each lane: full row for q=32w+l31, split with lane^32) ---
    float mx = -INFINITY;
#pragma unroll
    for (int t = 0; t < 4; ++t)
#pragma unroll
      for (int r = 0; r < 16; ++r) { accS[t][r] *= scale; mx = fmaxf(mx, accS[t][r]); }
    mx = fmaxf(mx, __shfl_xor(mx, 32));
    float sum = 0.f;
#pragma unroll
    for (int t = 0; t < 4; ++t)
#pragma unroll
      for (int r = 0; r < 16; ++r) { float pv = __expf(accS[t][r] - mx); accS[t][r] = pv; sum += pv; }
    sum += __shfl_xor(sum, 32);
    const float inv = 1.f / sum;
#pragma unroll
    for (int t = 0; t < 4; ++t)
#pragma unroll
      for (int r = 0; r < 16; ++r) accS[t][r] *= inv;

    // --- PV: P A-frags in-register; V frags read direct from LDS ---
    f32x16 accO[2];
#pragma unroll
    for (int nt = 0; nt < 2; ++nt)
#pragma unroll
      for (int r = 0; r < 16; ++r) accO[nt][r] = 0.f;

#pragma unroll
    for (int t = 0; t < 4; ++t) {
      union { unsigned int u[4]; f16x8 v; } fa, fb;
      {
        unsigned int a0 = pkh(accS[t][0], accS[t][1]);
        unsigned int a1 = pkh(accS[t][2], accS[t][3]);
        unsigned int b0 = pkh(accS[t][4], accS[t][5]);
        unsigned int b1 = pkh(accS[t][6], accS[t][7]);
        unsigned int sa0 = __shfl_xor(a0, 32), sa1 = __shfl_xor(a1, 32);
        unsigned int sb0 = __shfl_xor(b0, 32), sb1 = __shfl_xor(b1, 32);
        fa.u[0] = hl ? sb0 : a0; fa.u[1] = hl ? sb1 : a1;
        fa.u[2] = hl ? b0 : sa0; fa.u[3] = hl ? b1 : sa1;
      }
      {
        unsigned int a0 = pkh(accS[t][8], accS[t][9]);
        unsigned int a1 = pkh(accS[t][10], accS[t][11]);
        unsigned int b0 = pkh(accS[t][12], accS[t][13]);
        unsigned int b1 = pkh(accS[t][14], accS[t][15]);
        unsigned int sa0 = __shfl_xor(a0, 32), sa1 = __shfl_xor(a1, 32);
        unsigned int sb0 = __shfl_xor(b0, 32), sb1 = __shfl_xor(b1, 32);
        fb.u[0] = hl ? sb0 : a0; fb.u[1] = hl ? sb1 : a1;
        fb.u[2] = hl ? b0 : sa0; fb.u[3] = hl ? b1 : sa1;
      }
      // V frag lane read: rows ks*16 + hl*8 + e, col nt*32 + l31 (d>=48 -> 0)
#pragma unroll
      for (int j = 0; j < 2; ++j) {
        const int ks = 2 * t + j;
        const int r0 = ks * 16 + hl * 8;
        f16x8 v0, v1;
        {
          const int d = l31;                 // nt=0, always < 48
#pragma unroll
          for (int e = 0; e < 8; ++e) v0[e] = vls[(r0 + e) * KVS + hh * 48 + d];
        }
        if (l31 < 16) {
          const int d = 32 + l31;            // nt=1
#pragma unroll
          for (int e = 0; e < 8; ++e) v1[e] = vls[(r0 + e) * KVS + hh * 48 + d];
        } else {
#pragma unroll
          for (int e = 0; e < 8; ++e) v1[e] = (_Float16)0.f;
        }
        const f16x8 pa = j ? fb.v : fa.v;
        accO[0] = __builtin_amdgcn_mfma_f32_32x32x16_f16(pa, v0, accO[0], 0, 0, 0);
        accO[1] = __builtin_amdgcn_mfma_f32_32x32x16_f16(pa, v1, accO[1], 0, 0, 0);
      }
    }

    // --- store to SORTED position (linear, coalesced), bf16 ---
#pragma unroll
    for (int r = 0; r < 16; ++r) {
      int rowl = w * 32 + (r & 3) + 8 * (r >> 2) + 4 * hl;
      int sg = g * GS + rowl;
      if (sg < NN) {
        size_t base = ((size_t)b * XROWS + sg) * DIM + hd * HD;
        attn_out[base + l31] = __float2bfloat16(accO[0][r]);
        if (l31 < 16) attn_out[base + 32 + l31] = __float2bfloat16(accO[1][r]);
      }
    }
  }
}

// ---------------- K6a: pack W into MFMA B-fragment order ------------------
__global__ void k_wpack(const float* __restrict__ W, unsigned short* __restrict__ wpack) {
  int idx = blockIdx.x * blockDim.x + threadIdx.x;
  if (idx >= 12 * 6 * 64) return;
  int lane = idx & 63;
  int kkjt = idx >> 6;
  int kk = kkjt % 6;
  int jt = kkjt / 6;
  int j = jt * 16 + (lane & 15);
  int k0 = kk * 32 + (lane >> 4) * 8;
  const float* src = W + (size_t)j * DIM + k0;
  unsigned short tmp[8];
#pragma unroll
  for (int e = 0; e < 8; ++e) tmp[e] = f2bf(src[e]);
  ((u16x8*)wpack)[idx] = *(const u16x8*)tmp;
}

// ---------------- K6b: projection (reads sorted x, scatters out) ----------
__global__ __launch_bounds__(256) void k_proj_mfma(const unsigned short* __restrict__ xb,
                                                   const int* __restrict__ sidx,
                                                   const unsigned short* __restrict__ wpack,
                                                   const float* __restrict__ bias,
                                                   float* __restrict__ out) {
  __shared__ unsigned short wl[12 * 6 * 64 * 8];   // 72 KB
  const int tid = threadIdx.x;

  // async stage: chunk c dest = base + c*16 (lane-linear per wave)
#pragma unroll
  for (int j = 0; j < 18; ++j) {
    int c = j * 256 + tid;
    gload_lds16((const float*)((const u16x8*)wpack + c), (float*)((u16x8*)wl + c));
  }

  const int wid = tid >> 6, lane = tid & 63;
  const int l15 = lane & 15, lk = lane >> 4;

  float bv[12];
#pragma unroll
  for (int jt = 0; jt < 12; ++jt) bv[jt] = bias[jt * 16 + l15];

  __syncthreads();   // drains gload_lds vmcnt

  for (int tile = blockIdx.x; tile < BB * XTILES_B; tile += gridDim.x) {
    const int b = tile / XTILES_B;
    const int r0 = (tile % XTILES_B) * 64 + wid * 16;   // sorted-row base
    f32x4 acc[12];
#pragma unroll
    for (int jt = 0; jt < 12; ++jt) { f32x4 t = {bv[jt], bv[jt], bv[jt], bv[jt]}; acc[jt] = t; }

    const unsigned short* xrow = xb + ((size_t)b * XROWS + r0 + l15) * DIM;
#pragma unroll
    for (int kk = 0; kk < 6; ++kk) {
      bf16x8 a = *(const bf16x8*)(xrow + kk * 32 + lk * 8);
#pragma unroll
      for (int jt = 0; jt < 12; ++jt) {
        bf16x8 bfr = *(const bf16x8*)(wl + ((jt * 6 + kk) * 64 + lane) * 8);
        acc[jt] = __builtin_amdgcn_mfma_f32_16x16x32_bf16(a, bfr, acc[jt], 0, 0, 0);
      }
    }

    const int rowb = r0 + lk * 4;
    int orow[4];
#pragma unroll
    for (int r = 0; r < 4; ++r)
      orow[r] = (rowb + r < NN) ? sidx[b * NN + rowb + r] : -1;

#pragma unroll
    for (int jt = 0; jt < 12; ++jt) {
#pragma unroll
      for (int r = 0; r < 4; ++r) {
        if (orow[r] >= 0)
          out[((size_t)b * NN + orow[r]) * DIM + jt * 16 + l15] = acc[jt][r];
      }
    }
  }
}

// ---------------- launch --------------------------------------------------
extern "C" void kernel_launch(void* const* d_in, const int* in_sizes, int n_in,
                              void* d_out, int out_size, void* d_ws, size_t ws_size,
                              hipStream_t stream) {
  const float* qkv = (const float*)d_in[0];
  const float* sim = (const float*)d_in[1];
  const float* proj_w = (const float*)d_in[2];
  const float* proj_b = (const float*)d_in[3];
  const float* logit_scale = (const float*)d_in[4];

  unsigned short* x_bf16 = (unsigned short*)d_ws;                 // BB*XROWS*DIM bf16
  unsigned short* wpack = x_bf16 + (size_t)BB * XROWS * DIM;      // 12*6*64*8
  int* tk = (int*)(wpack + 12 * 6 * 64 * 8);                      // BB*NN
  int* hist = tk + (size_t)BB * NN;                               // BB*NBLK*MM
  int* boff = hist + (size_t)BB * NBLK * MM;                      // BB*NBLK*MM
  int* sidx = boff + (size_t)BB * NBLK * MM;                      // BB*NN

  k_argmax_hist<<<dim3(NBLK, BB), SORT_TPB, 0, stream>>>(sim, tk, hist);
  k_scan<<<BB, 1024, 0, stream>>>(hist, boff);
  k_scatter<<<dim3(NBLK, BB), SORT_TPB, 0, stream>>>(tk, boff, sidx);
  k_wpack<<<(12 * 6 * 64 + 255) / 256, 256, 0, stream>>>(proj_w, wpack);
  k_attn_mfma<<<dim3(1024, 1, BB), 256, 0, stream>>>(qkv, sidx, logit_scale,
                                                     (__hip_bfloat16*)x_bf16);
  k_proj_mfma<<<dim3(1016), 256, 0, stream>>>(x_bf16, sidx, wpack, proj_b, (float*)d_out);
}